// Round 1
// baseline (1864.153 us; speedup 1.0000x reference)
//
#include <hip/hip_runtime.h>
#include <hip/hip_bf16.h>
#include <hip/hip_fp16.h>

#define DEVINL __device__ __forceinline__

typedef _Float16 f16x8 __attribute__((ext_vector_type(8)));
typedef float f32x4 __attribute__((ext_vector_type(4)));
typedef float f32x4v __attribute__((ext_vector_type(4)));
typedef unsigned short u16x4 __attribute__((ext_vector_type(4)));
typedef unsigned short u16x8 __attribute__((ext_vector_type(8)));

DEVINL unsigned short f2h(float x) {
    _Float16 h = (_Float16)x;
    return __builtin_bit_cast(unsigned short, h);
}

// ---------------------------------------------------------------------------
// Kernel 1: projection GEMM.  out[m, o] = relu( sum_h A[m,h] * W[o,h] + b[o] )
// A fp32 [M x 1024] row-major, W fp32 [1024 x 1024] row-major (o rows),
// out fp16 [M x 1024].  Tile 128x128, BK=32, 4 waves (2x2), 16x16x32 MFMA.
// ---------------------------------------------------------------------------
__global__ __launch_bounds__(256) void proj_kernel(
    const float* __restrict__ A, const float* __restrict__ W,
    const float* __restrict__ bias, unsigned short* __restrict__ out)
{
    __shared__ __attribute__((aligned(16))) unsigned short At[128 * 32];
    __shared__ __attribute__((aligned(16))) unsigned short Bt[128 * 32];

    const int t    = threadIdx.x;
    const int lane = t & 63;
    const int wave = t >> 6;
    const int wr   = wave >> 1;   // wave row (0..1) -> 64 rows
    const int wc   = wave & 1;    // wave col (0..1) -> 64 cols
    const int m0   = blockIdx.y * 128;
    const int n0   = blockIdx.x * 128;
    const int K    = 1024;

    const int sr = t >> 3;        // staging row base (0..31)
    const int sq = t & 7;         // staging quarter (float4) within 32-float row

    const int fr = lane & 15;     // fragment row/col within 16
    const int kg = lane >> 4;     // k-group (0..3)

    f32x4 acc[4][4] = {};

    for (int k0 = 0; k0 < K; k0 += 32) {
        __syncthreads();
#pragma unroll
        for (int p = 0; p < 4; ++p) {
            int r = sr + p * 32;
            f32x4v av = *(const f32x4v*)&A[(size_t)(m0 + r) * K + k0 + sq * 4];
            f32x4v wv = *(const f32x4v*)&W[(size_t)(n0 + r) * K + k0 + sq * 4];
            u16x4 ah, wh;
#pragma unroll
            for (int e = 0; e < 4; ++e) { ah[e] = f2h(av[e]); wh[e] = f2h(wv[e]); }
            *(u16x4*)&At[r * 32 + sq * 4] = ah;
            *(u16x4*)&Bt[r * 32 + sq * 4] = wh;
        }
        __syncthreads();

        f16x8 af[4], bf[4];
#pragma unroll
        for (int i = 0; i < 4; ++i) {
            af[i] = __builtin_bit_cast(f16x8, *(const u16x8*)&At[(wr * 64 + i * 16 + fr) * 32 + kg * 8]);
            bf[i] = __builtin_bit_cast(f16x8, *(const u16x8*)&Bt[(wc * 64 + i * 16 + fr) * 32 + kg * 8]);
        }
#pragma unroll
        for (int i = 0; i < 4; ++i)
#pragma unroll
            for (int j = 0; j < 4; ++j)
                acc[i][j] = __builtin_amdgcn_mfma_f32_16x16x32_f16(af[i], bf[j], acc[i][j], 0, 0, 0);
    }

    // epilogue: C/D layout col = lane&15, row = (lane>>4)*4 + reg
#pragma unroll
    for (int i = 0; i < 4; ++i) {
        int row = m0 + wr * 64 + i * 16 + kg * 4;
#pragma unroll
        for (int j = 0; j < 4; ++j) {
            int col = n0 + wc * 64 + j * 16 + fr;
            float bv = bias[col];
#pragma unroll
            for (int r2 = 0; r2 < 4; ++r2) {
                float v = acc[i][j][r2] + bv;
                v = v > 0.f ? v : 0.f;
                out[(size_t)(row + r2) * 1024 + col] = f2h(v);
            }
        }
    }
}

// ---------------------------------------------------------------------------
// Kernel 2: scores GEMM per batch.  S[i,j] = sum_h xp[i,h]*yp[j,h]; mask -> -1e30
// xp, yp fp16 [2048 x 1024]; S fp32 [2048 x 2048]
// ---------------------------------------------------------------------------
__global__ __launch_bounds__(256) void scores_kernel(
    const unsigned short* __restrict__ XP, const unsigned short* __restrict__ YP,
    const int* __restrict__ ymask, float* __restrict__ S)
{
    __shared__ __attribute__((aligned(16))) unsigned short At[128 * 32];
    __shared__ __attribute__((aligned(16))) unsigned short Bt[128 * 32];

    const int b = blockIdx.z;
    const unsigned short* A = XP + (size_t)b * 2048 * 1024;
    const unsigned short* B = YP + (size_t)b * 2048 * 1024;
    const int* mk = ymask + b * 2048;
    float* Sb = S + (size_t)b * 2048 * 2048;

    const int t    = threadIdx.x;
    const int lane = t & 63;
    const int wave = t >> 6;
    const int wr = wave >> 1, wc = wave & 1;
    const int m0 = blockIdx.y * 128;
    const int n0 = blockIdx.x * 128;
    const int K  = 1024;

    const int sr = t >> 2;   // 0..63
    const int sq = t & 3;    // 16B chunk within 64B row
    const int fr = lane & 15;
    const int kg = lane >> 4;

    f32x4 acc[4][4] = {};

    for (int k0 = 0; k0 < K; k0 += 32) {
        __syncthreads();
#pragma unroll
        for (int p = 0; p < 2; ++p) {
            int r = sr + p * 64;
            *(u16x8*)&At[r * 32 + sq * 8] = *(const u16x8*)&A[(size_t)(m0 + r) * 1024 + k0 + sq * 8];
            *(u16x8*)&Bt[r * 32 + sq * 8] = *(const u16x8*)&B[(size_t)(n0 + r) * 1024 + k0 + sq * 8];
        }
        __syncthreads();

        f16x8 af[4], bf[4];
#pragma unroll
        for (int i = 0; i < 4; ++i) {
            af[i] = __builtin_bit_cast(f16x8, *(const u16x8*)&At[(wr * 64 + i * 16 + fr) * 32 + kg * 8]);
            bf[i] = __builtin_bit_cast(f16x8, *(const u16x8*)&Bt[(wc * 64 + i * 16 + fr) * 32 + kg * 8]);
        }
#pragma unroll
        for (int i = 0; i < 4; ++i)
#pragma unroll
            for (int j = 0; j < 4; ++j)
                acc[i][j] = __builtin_amdgcn_mfma_f32_16x16x32_f16(af[i], bf[j], acc[i][j], 0, 0, 0);
    }

#pragma unroll
    for (int i = 0; i < 4; ++i) {
        int row = m0 + wr * 64 + i * 16 + kg * 4;
#pragma unroll
        for (int j = 0; j < 4; ++j) {
            int col = n0 + wc * 64 + j * 16 + fr;
            bool masked = mk[col] != 0;
#pragma unroll
            for (int r2 = 0; r2 < 4; ++r2) {
                float v = masked ? -1e30f : acc[i][j][r2];
                Sb[(size_t)(row + r2) * 2048 + col] = v;
            }
        }
    }
}

// ---------------------------------------------------------------------------
// Kernel 3: row softmax.  alpha[row, :] = softmax(S[row, :]) as fp16.
// One 256-thread block per row (2048 cols, 8 per thread).
// ---------------------------------------------------------------------------
__global__ __launch_bounds__(256) void softmax_kernel(
    const float* __restrict__ S, unsigned short* __restrict__ alpha)
{
    const size_t row = blockIdx.x;
    const float* s = S + row * 2048;
    unsigned short* a = alpha + row * 2048;
    const int t = threadIdx.x;
    const int lane = t & 63;
    const int wave = t >> 6;

    __shared__ float redm[4];
    __shared__ float reds[4];

    f32x4v v0 = *(const f32x4v*)&s[t * 8];
    f32x4v v1 = *(const f32x4v*)&s[t * 8 + 4];

    float m = -3.4e38f;
#pragma unroll
    for (int e = 0; e < 4; ++e) { m = fmaxf(m, v0[e]); m = fmaxf(m, v1[e]); }
#pragma unroll
    for (int o = 1; o < 64; o <<= 1) m = fmaxf(m, __shfl_xor(m, o));
    if (lane == 0) redm[wave] = m;
    __syncthreads();
    m = fmaxf(fmaxf(redm[0], redm[1]), fmaxf(redm[2], redm[3]));

    float e0[4], e1[4];
    float sum = 0.f;
#pragma unroll
    for (int e = 0; e < 4; ++e) {
        e0[e] = __expf(v0[e] - m); sum += e0[e];
        e1[e] = __expf(v1[e] - m); sum += e1[e];
    }
#pragma unroll
    for (int o = 1; o < 64; o <<= 1) sum += __shfl_xor(sum, o);
    if (lane == 0) reds[wave] = sum;
    __syncthreads();
    sum = reds[0] + reds[1] + reds[2] + reds[3];
    float inv = 1.f / sum;

    u16x4 o0, o1;
#pragma unroll
    for (int e = 0; e < 4; ++e) { o0[e] = f2h(e0[e] * inv); o1[e] = f2h(e1[e] * inv); }
    *(u16x4*)&a[t * 8]     = o0;
    *(u16x4*)&a[t * 8 + 4] = o1;
}

// ---------------------------------------------------------------------------
// Kernel 4: PV GEMM per batch.  O[i,h] = sum_j alpha[i,j] * y[j,h]
// alpha fp16 [2048 x 2048] (K contiguous); y fp32 [2048 x 1024] (transposed
// into LDS as fp16 [128 h][32 j]); O fp32 out.
// ---------------------------------------------------------------------------
__global__ __launch_bounds__(256) void pv_kernel(
    const unsigned short* __restrict__ AL, const float* __restrict__ Y,
    float* __restrict__ O)
{
    __shared__ __attribute__((aligned(16))) unsigned short At[128 * 32];
    __shared__ __attribute__((aligned(16))) unsigned short Bt[128 * 32];

    const int b = blockIdx.z;
    const unsigned short* A = AL + (size_t)b * 2048 * 2048;
    const float* Yb = Y + (size_t)b * 2048 * 1024;
    float* Ob = O + (size_t)b * 2048 * 1024;

    const int t    = threadIdx.x;
    const int lane = t & 63;
    const int wave = t >> 6;
    const int wr = wave >> 1, wc = wave & 1;
    const int m0 = blockIdx.y * 128;  // i tile
    const int n0 = blockIdx.x * 128;  // h tile
    const int K  = 2048;              // j

    const int sra = t >> 2;  // alpha staging row 0..63
    const int sqa = t & 3;
    const int srb = t >> 5;  // y staging row 0..7
    const int sqb = t & 31;  // y staging float4 index (h quarter)
    const int fr = lane & 15;
    const int kg = lane >> 4;

    f32x4 acc[4][4] = {};

    for (int k0 = 0; k0 < K; k0 += 32) {
        __syncthreads();
#pragma unroll
        for (int p = 0; p < 2; ++p) {
            int r = sra + p * 64;
            *(u16x8*)&At[r * 32 + sqa * 8] = *(const u16x8*)&A[(size_t)(m0 + r) * 2048 + k0 + sqa * 8];
        }
#pragma unroll
        for (int p = 0; p < 4; ++p) {
            int r = srb + p * 8;  // j within tile (0..31)
            f32x4v yv = *(const f32x4v*)&Yb[(size_t)(k0 + r) * 1024 + n0 + sqb * 4];
#pragma unroll
            for (int e = 0; e < 4; ++e)
                Bt[(sqb * 4 + e) * 32 + r] = f2h(yv[e]);  // transposed: [h][j]
        }
        __syncthreads();

        f16x8 af[4], bf[4];
#pragma unroll
        for (int i = 0; i < 4; ++i) {
            af[i] = __builtin_bit_cast(f16x8, *(const u16x8*)&At[(wr * 64 + i * 16 + fr) * 32 + kg * 8]);
            bf[i] = __builtin_bit_cast(f16x8, *(const u16x8*)&Bt[(wc * 64 + i * 16 + fr) * 32 + kg * 8]);
        }
#pragma unroll
        for (int i = 0; i < 4; ++i)
#pragma unroll
            for (int j = 0; j < 4; ++j)
                acc[i][j] = __builtin_amdgcn_mfma_f32_16x16x32_f16(af[i], bf[j], acc[i][j], 0, 0, 0);
    }

#pragma unroll
    for (int i = 0; i < 4; ++i) {
        int row = m0 + wr * 64 + i * 16 + kg * 4;
#pragma unroll
        for (int j = 0; j < 4; ++j) {
            int col = n0 + wc * 64 + j * 16 + fr;
#pragma unroll
            for (int r2 = 0; r2 < 4; ++r2)
                Ob[(size_t)(row + r2) * 1024 + col] = acc[i][j][r2];
        }
    }
}

// ---------------------------------------------------------------------------
extern "C" void kernel_launch(void* const* d_in, const int* in_sizes, int n_in,
                              void* d_out, int out_size, void* d_ws, size_t ws_size,
                              hipStream_t stream)
{
    const float* x     = (const float*)d_in[0];   // [16, 2048, 1024]
    const float* y     = (const float*)d_in[1];   // [16, 2048, 1024]
    const int*   ymask = (const int*)d_in[2];     // [16, 2048] (bool -> int32)
    const float* W     = (const float*)d_in[3];   // [1024, 1024]
    const float* bias  = (const float*)d_in[4];   // [1024]
    float* out = (float*)d_out;                   // [16, 2048, 1024] fp32

    // workspace layout (384 MiB):
    //   S     fp32 [16*2048*2048]        @ 0        (256 MiB)
    //   xp    fp16 [16*2048*1024]        @ 256 MiB  (64 MiB)
    //   yp    fp16 [16*2048*1024]        @ 320 MiB  (64 MiB)
    //   alpha fp16 [16*2048*2048]        @ 256 MiB  (aliases xp+yp, dead by then)
    const size_t S_OFF  = 0;
    const size_t XP_OFF = 268435456;          // 256 MiB
    const size_t YP_OFF = XP_OFF + 67108864;  // +64 MiB
    const size_t NEED   = XP_OFF + 134217728; // 384 MiB total
    if (ws_size < NEED) return;  // clean failure marker: output stays zero

    char* ws = (char*)d_ws;
    float* S = (float*)(ws + S_OFF);
    unsigned short* xp    = (unsigned short*)(ws + XP_OFF);
    unsigned short* yp    = (unsigned short*)(ws + YP_OFF);
    unsigned short* alpha = (unsigned short*)(ws + XP_OFF);  // alias

    dim3 blk(256);
    proj_kernel<<<dim3(8, 256), blk, 0, stream>>>(x, W, bias, xp);
    proj_kernel<<<dim3(8, 256), blk, 0, stream>>>(y, W, bias, yp);
    scores_kernel<<<dim3(16, 16, 16), blk, 0, stream>>>(xp, yp, ymask, S);
    softmax_kernel<<<dim3(32768), blk, 0, stream>>>(S, alpha);
    pv_kernel<<<dim3(8, 16, 16), blk, 0, stream>>>(alpha, y, out);
}

// Round 4
// 1133.739 us; speedup vs baseline: 1.6443x; 1.6443x over previous
//
#include <hip/hip_runtime.h>
#include <hip/hip_bf16.h>
#include <hip/hip_fp16.h>

#define DEVINL __device__ __forceinline__

typedef _Float16 f16x8 __attribute__((ext_vector_type(8)));
typedef float f32x4 __attribute__((ext_vector_type(4)));
typedef float f32x4v __attribute__((ext_vector_type(4)));
typedef unsigned short u16x4 __attribute__((ext_vector_type(4)));
typedef unsigned short u16x8 __attribute__((ext_vector_type(8)));

DEVINL unsigned short f2h(float x) {
    _Float16 h = (_Float16)x;
    return __builtin_bit_cast(unsigned short, h);
}

// async global->LDS, 16B per lane. LDS dest must be linear (base + lane*16).
DEVINL void gload16(const void* g, void* l) {
    __builtin_amdgcn_global_load_lds(
        (const __attribute__((address_space(1))) void*)g,
        (__attribute__((address_space(3))) void*)l, 16, 0, 0);
}

// ---------------------------------------------------------------------------
// Kernel 1: projection GEMM.  out[m, o] = relu( sum_h A[m,h] * W[o,h] + b[o] )
// A fp32 [M x 1024], W fp32 [1024 x 1024] (o rows), out fp16 [M x 1024].
// Reg-staged (fp32->fp16 convert during staging). 128x128 tile, BK=32, 4 waves.
// ---------------------------------------------------------------------------
__global__ __launch_bounds__(256) void proj_kernel(
    const float* __restrict__ A, const float* __restrict__ W,
    const float* __restrict__ bias, unsigned short* __restrict__ out)
{
    __shared__ __attribute__((aligned(16))) unsigned short At[128 * 32];
    __shared__ __attribute__((aligned(16))) unsigned short Bt[128 * 32];

    const int t    = threadIdx.x;
    const int lane = t & 63;
    const int wave = t >> 6;
    const int wr   = wave >> 1;
    const int wc   = wave & 1;
    const int m0   = blockIdx.y * 128;
    const int n0   = blockIdx.x * 128;
    const int K    = 1024;

    const int sr = t >> 3;        // staging row base (0..31)
    const int sq = t & 7;         // float4 quarter within 32-float row

    const int fr = lane & 15;
    const int kg = lane >> 4;

    f32x4 acc[4][4] = {};

    for (int k0 = 0; k0 < K; k0 += 32) {
        __syncthreads();
#pragma unroll
        for (int p = 0; p < 4; ++p) {
            int r = sr + p * 32;
            f32x4v av = *(const f32x4v*)&A[(size_t)(m0 + r) * K + k0 + sq * 4];
            f32x4v wv = *(const f32x4v*)&W[(size_t)(n0 + r) * K + k0 + sq * 4];
            u16x4 ah, wh;
#pragma unroll
            for (int e = 0; e < 4; ++e) { ah[e] = f2h(av[e]); wh[e] = f2h(wv[e]); }
            *(u16x4*)&At[r * 32 + sq * 4] = ah;
            *(u16x4*)&Bt[r * 32 + sq * 4] = wh;
        }
        __syncthreads();

        f16x8 af[4], bf[4];
#pragma unroll
        for (int i = 0; i < 4; ++i) {
            af[i] = __builtin_bit_cast(f16x8, *(const u16x8*)&At[(wr * 64 + i * 16 + fr) * 32 + kg * 8]);
            bf[i] = __builtin_bit_cast(f16x8, *(const u16x8*)&Bt[(wc * 64 + i * 16 + fr) * 32 + kg * 8]);
        }
#pragma unroll
        for (int i = 0; i < 4; ++i)
#pragma unroll
            for (int j = 0; j < 4; ++j)
                acc[i][j] = __builtin_amdgcn_mfma_f32_16x16x32_f16(af[i], bf[j], acc[i][j], 0, 0, 0);
    }

#pragma unroll
    for (int i = 0; i < 4; ++i) {
        int row = m0 + wr * 64 + i * 16 + kg * 4;
#pragma unroll
        for (int j = 0; j < 4; ++j) {
            int col = n0 + wc * 64 + j * 16 + fr;
            float bv = bias[col];
#pragma unroll
            for (int r2 = 0; r2 < 4; ++r2) {
                float v = acc[i][j][r2] + bv;
                v = v > 0.f ? v : 0.f;
                out[(size_t)(row + r2) * 1024 + col] = f2h(v);
            }
        }
    }
}

// ---------------------------------------------------------------------------
// Kernel 2: scores GEMM per batch.  S[i,j] = sum_h xp[i,h]*yp[j,h]; mask->-1e30
// xp, yp fp16 [2048 x 1024]; S fp32 [2048 x 2048].  global_load_lds staging.
// ---------------------------------------------------------------------------
__global__ __launch_bounds__(256) void scores_kernel(
    const unsigned short* __restrict__ XP, const unsigned short* __restrict__ YP,
    const int* __restrict__ ymask, float* __restrict__ S)
{
    __shared__ __attribute__((aligned(16))) unsigned short At[128 * 32];
    __shared__ __attribute__((aligned(16))) unsigned short Bt[128 * 32];

    const int b = blockIdx.z;
    const unsigned short* A = XP + (size_t)b * 2048 * 1024;
    const unsigned short* B = YP + (size_t)b * 2048 * 1024;
    const int* mk = ymask + b * 2048;
    float* Sb = S + (size_t)b * 2048 * 2048;

    const int t    = threadIdx.x;
    const int lane = t & 63;
    const int wave = t >> 6;
    const int wr = wave >> 1, wc = wave & 1;
    const int m0 = blockIdx.y * 128;
    const int n0 = blockIdx.x * 128;
    const int K  = 1024;

    const int sr = t >> 2;   // 0..63
    const int sq = t & 3;    // 16B chunk within 64B row
    const int fr = lane & 15;
    const int kg = lane >> 4;

    f32x4 acc[4][4] = {};

    for (int k0 = 0; k0 < K; k0 += 32) {
        __syncthreads();
        // async staging: LDS layout is linear (offset = t*16B per half-tile)
        gload16(&A[(size_t)(m0 + sr)      * 1024 + k0 + sq * 8], &At[t * 8]);
        gload16(&A[(size_t)(m0 + sr + 64) * 1024 + k0 + sq * 8], &At[2048 + t * 8]);
        gload16(&B[(size_t)(n0 + sr)      * 1024 + k0 + sq * 8], &Bt[t * 8]);
        gload16(&B[(size_t)(n0 + sr + 64) * 1024 + k0 + sq * 8], &Bt[2048 + t * 8]);
        __syncthreads();

        f16x8 af[4], bf[4];
#pragma unroll
        for (int i = 0; i < 4; ++i) {
            af[i] = __builtin_bit_cast(f16x8, *(const u16x8*)&At[(wr * 64 + i * 16 + fr) * 32 + kg * 8]);
            bf[i] = __builtin_bit_cast(f16x8, *(const u16x8*)&Bt[(wc * 64 + i * 16 + fr) * 32 + kg * 8]);
        }
#pragma unroll
        for (int i = 0; i < 4; ++i)
#pragma unroll
            for (int j = 0; j < 4; ++j)
                acc[i][j] = __builtin_amdgcn_mfma_f32_16x16x32_f16(af[i], bf[j], acc[i][j], 0, 0, 0);
    }

#pragma unroll
    for (int i = 0; i < 4; ++i) {
        int row = m0 + wr * 64 + i * 16 + kg * 4;
#pragma unroll
        for (int j = 0; j < 4; ++j) {
            int col = n0 + wc * 64 + j * 16 + fr;
            bool masked = mk[col] != 0;
#pragma unroll
            for (int r2 = 0; r2 < 4; ++r2) {
                float v = masked ? -1e30f : acc[i][j][r2];
                Sb[(size_t)(row + r2) * 2048 + col] = v;
            }
        }
    }
}

// ---------------------------------------------------------------------------
// Kernel 3: row softmax.  alpha[row, :] = softmax(S[row, :]) as fp16.
// ---------------------------------------------------------------------------
__global__ __launch_bounds__(256) void softmax_kernel(
    const float* __restrict__ S, unsigned short* __restrict__ alpha)
{
    const size_t row = blockIdx.x;
    const float* s = S + row * 2048;
    unsigned short* a = alpha + row * 2048;
    const int t = threadIdx.x;
    const int lane = t & 63;
    const int wave = t >> 6;

    __shared__ float redm[4];
    __shared__ float reds[4];

    f32x4v v0 = *(const f32x4v*)&s[t * 8];
    f32x4v v1 = *(const f32x4v*)&s[t * 8 + 4];

    float m = -3.4e38f;
#pragma unroll
    for (int e = 0; e < 4; ++e) { m = fmaxf(m, v0[e]); m = fmaxf(m, v1[e]); }
#pragma unroll
    for (int o = 1; o < 64; o <<= 1) m = fmaxf(m, __shfl_xor(m, o));
    if (lane == 0) redm[wave] = m;
    __syncthreads();
    m = fmaxf(fmaxf(redm[0], redm[1]), fmaxf(redm[2], redm[3]));

    float e0[4], e1[4];
    float sum = 0.f;
#pragma unroll
    for (int e = 0; e < 4; ++e) {
        e0[e] = __expf(v0[e] - m); sum += e0[e];
        e1[e] = __expf(v1[e] - m); sum += e1[e];
    }
#pragma unroll
    for (int o = 1; o < 64; o <<= 1) sum += __shfl_xor(sum, o);
    if (lane == 0) reds[wave] = sum;
    __syncthreads();
    sum = reds[0] + reds[1] + reds[2] + reds[3];
    float inv = 1.f / sum;

    u16x4 o0, o1;
#pragma unroll
    for (int e = 0; e < 4; ++e) { o0[e] = f2h(e0[e] * inv); o1[e] = f2h(e1[e] * inv); }
    *(u16x4*)&a[t * 8]     = o0;
    *(u16x4*)&a[t * 8 + 4] = o1;
}

// ---------------------------------------------------------------------------
// Kernel 4: y transpose+convert.  yT[b][h][j] fp16 from y[b][j][h] fp32.
// 64x64 tiles via LDS (fp32 [64][65], pad kills bank conflicts both sides).
// ---------------------------------------------------------------------------
__global__ __launch_bounds__(256) void transpose_y_kernel(
    const float* __restrict__ Y, unsigned short* __restrict__ YT)
{
    __shared__ float T[64][65];
    const int b  = blockIdx.z;
    const float* Yb = Y + (size_t)b * 2048 * 1024;
    unsigned short* Tb = YT + (size_t)b * 1024 * 2048;
    const int j0 = blockIdx.y * 64;
    const int h0 = blockIdx.x * 64;
    const int t = threadIdx.x;

    const int jr = t >> 4;    // 0..15
    const int hc = t & 15;    // float4 chunk
#pragma unroll
    for (int p = 0; p < 4; ++p) {
        int j = jr + p * 16;
        f32x4v v = *(const f32x4v*)&Yb[(size_t)(j0 + j) * 1024 + h0 + hc * 4];
#pragma unroll
        for (int e = 0; e < 4; ++e) T[j][hc * 4 + e] = v[e];
    }
    __syncthreads();

    const int hr = t >> 3;    // 0..31
    const int jc = t & 7;     // u16x8 chunk
#pragma unroll
    for (int p = 0; p < 2; ++p) {
        int h = hr + p * 32;
        u16x8 o;
#pragma unroll
        for (int e = 0; e < 8; ++e) o[e] = f2h(T[jc * 8 + e][h]);
        *(u16x8*)&Tb[(size_t)(h0 + h) * 2048 + j0 + jc * 8] = o;
    }
}

// ---------------------------------------------------------------------------
// Kernel 5: PV GEMM per batch.  O[i,h] = sum_j alpha[i,j] * yT[h,j]
// alpha fp16 [2048 x 2048], yT fp16 [1024 x 2048]; O fp32.
// Same structure as scores (both operands k-contiguous), gload_lds staging.
// ---------------------------------------------------------------------------
__global__ __launch_bounds__(256) void pv_kernel(
    const unsigned short* __restrict__ AL, const unsigned short* __restrict__ YT,
    float* __restrict__ O)
{
    __shared__ __attribute__((aligned(16))) unsigned short At[128 * 32];
    __shared__ __attribute__((aligned(16))) unsigned short Bt[128 * 32];

    const int b = blockIdx.z;
    const unsigned short* A = AL + (size_t)b * 2048 * 2048;
    const unsigned short* B = YT + (size_t)b * 1024 * 2048;
    float* Ob = O + (size_t)b * 2048 * 1024;

    const int t    = threadIdx.x;
    const int lane = t & 63;
    const int wave = t >> 6;
    const int wr = wave >> 1, wc = wave & 1;
    const int m0 = blockIdx.y * 128;  // i tile
    const int n0 = blockIdx.x * 128;  // h tile
    const int K  = 2048;              // j

    const int sr = t >> 2;
    const int sq = t & 3;
    const int fr = lane & 15;
    const int kg = lane >> 4;

    f32x4 acc[4][4] = {};

    for (int k0 = 0; k0 < K; k0 += 32) {
        __syncthreads();
        gload16(&A[(size_t)(m0 + sr)      * 2048 + k0 + sq * 8], &At[t * 8]);
        gload16(&A[(size_t)(m0 + sr + 64) * 2048 + k0 + sq * 8], &At[2048 + t * 8]);
        gload16(&B[(size_t)(n0 + sr)      * 2048 + k0 + sq * 8], &Bt[t * 8]);
        gload16(&B[(size_t)(n0 + sr + 64) * 2048 + k0 + sq * 8], &Bt[2048 + t * 8]);
        __syncthreads();

        f16x8 af[4], bf[4];
#pragma unroll
        for (int i = 0; i < 4; ++i) {
            af[i] = __builtin_bit_cast(f16x8, *(const u16x8*)&At[(wr * 64 + i * 16 + fr) * 32 + kg * 8]);
            bf[i] = __builtin_bit_cast(f16x8, *(const u16x8*)&Bt[(wc * 64 + i * 16 + fr) * 32 + kg * 8]);
        }
#pragma unroll
        for (int i = 0; i < 4; ++i)
#pragma unroll
            for (int j = 0; j < 4; ++j)
                acc[i][j] = __builtin_amdgcn_mfma_f32_16x16x32_f16(af[i], bf[j], acc[i][j], 0, 0, 0);
    }

#pragma unroll
    for (int i = 0; i < 4; ++i) {
        int row = m0 + wr * 64 + i * 16 + kg * 4;
#pragma unroll
        for (int j = 0; j < 4; ++j) {
            int col = n0 + wc * 64 + j * 16 + fr;
#pragma unroll
            for (int r2 = 0; r2 < 4; ++r2)
                Ob[(size_t)(row + r2) * 1024 + col] = acc[i][j][r2];
        }
    }
}

// ---------------------------------------------------------------------------
extern "C" void kernel_launch(void* const* d_in, const int* in_sizes, int n_in,
                              void* d_out, int out_size, void* d_ws, size_t ws_size,
                              hipStream_t stream)
{
    const float* x     = (const float*)d_in[0];   // [16, 2048, 1024]
    const float* y     = (const float*)d_in[1];   // [16, 2048, 1024]
    const int*   ymask = (const int*)d_in[2];     // [16, 2048]
    const float* W     = (const float*)d_in[3];   // [1024, 1024]
    const float* bias  = (const float*)d_in[4];   // [1024]
    float* out = (float*)d_out;                   // [16, 2048, 1024] fp32

    // workspace layout (384 MiB), time-multiplexed:
    //   phase A (proj):      xp fp16 @256M (64M), yp fp16 @320M (64M)
    //   phase B (scores):    S fp32 @0 (256M)           [reads xp, yp]
    //   phase C (softmax):   alpha fp16 @256M (128M)    [overwrites xp+yp, dead]
    //   phase D (transpose): yT fp16 @0 (128M)          [overwrites S, dead]
    //   phase E (pv):        reads alpha@256M + yT@0 -> out
    const size_t S_OFF  = 0;
    const size_t XP_OFF = 268435456;          // 256 MiB
    const size_t YP_OFF = XP_OFF + 67108864;  // +64 MiB
    const size_t NEED   = XP_OFF + 134217728; // 384 MiB total
    if (ws_size < NEED) return;

    char* ws = (char*)d_ws;
    float* S = (float*)(ws + S_OFF);
    unsigned short* xp    = (unsigned short*)(ws + XP_OFF);
    unsigned short* yp    = (unsigned short*)(ws + YP_OFF);
    unsigned short* alpha = (unsigned short*)(ws + XP_OFF);  // alias (xp,yp dead)
    unsigned short* yT    = (unsigned short*)(ws + S_OFF);   // alias (S dead)

    dim3 blk(256);
    proj_kernel<<<dim3(8, 256), blk, 0, stream>>>(x, W, bias, xp);
    proj_kernel<<<dim3(8, 256), blk, 0, stream>>>(y, W, bias, yp);
    scores_kernel<<<dim3(16, 16, 16), blk, 0, stream>>>(xp, yp, ymask, S);
    softmax_kernel<<<dim3(32768), blk, 0, stream>>>(S, alpha);
    transpose_y_kernel<<<dim3(16, 32, 16), blk, 0, stream>>>(y, yT);
    pv_kernel<<<dim3(8, 16, 16), blk, 0, stream>>>(alpha, yT, out);
}

// Round 6
// 989.237 us; speedup vs baseline: 1.8844x; 1.1461x over previous
//
#include <hip/hip_runtime.h>
#include <hip/hip_bf16.h>
#include <hip/hip_fp16.h>

#define DEVINL __device__ __forceinline__

typedef _Float16 f16x8 __attribute__((ext_vector_type(8)));
typedef float f32x4 __attribute__((ext_vector_type(4)));
typedef float f32x4v __attribute__((ext_vector_type(4)));
typedef unsigned short u16x4 __attribute__((ext_vector_type(4)));
typedef unsigned short u16x8 __attribute__((ext_vector_type(8)));

DEVINL unsigned short f2h(float x) {
    _Float16 h = (_Float16)x;
    return __builtin_bit_cast(unsigned short, h);
}

// async global->LDS, 16B per lane. LDS dest must be linear (base + lane*16).
DEVINL void gload16(const void* g, void* l) {
    __builtin_amdgcn_global_load_lds(
        (const __attribute__((address_space(1))) void*)g,
        (__attribute__((address_space(3))) void*)l, 16, 0, 0);
}

// raw barrier fenced against compiler memory-op reordering (no vmcnt(0) drain)
DEVINL void pipe_barrier() {
    asm volatile("" ::: "memory");
    __builtin_amdgcn_s_barrier();
    asm volatile("" ::: "memory");
}

// ---------------------------------------------------------------------------
// Kernel 0: fp32 -> fp16 convert (vectorized, grid-stride over 8-elem chunks)
// ---------------------------------------------------------------------------
__global__ __launch_bounds__(256) void cvt_kernel(
    const float* __restrict__ in, unsigned short* __restrict__ out, int n8)
{
    int i = blockIdx.x * 256 + threadIdx.x;
    int stride = gridDim.x * 256;
    for (; i < n8; i += stride) {
        f32x4v a = *(const f32x4v*)&in[(size_t)i * 8];
        f32x4v b = *(const f32x4v*)&in[(size_t)i * 8 + 4];
        u16x8 o;
#pragma unroll
        for (int e = 0; e < 4; ++e) { o[e] = f2h(a[e]); o[4 + e] = f2h(b[e]); }
        *(u16x8*)&out[(size_t)i * 8] = o;
    }
}

// ---------------------------------------------------------------------------
// Unified pipelined GEMM:  C[m,n] (+epilogue) = sum_k A[m,k] * B[n,k]
// A,B fp16 k-contiguous (row stride == K).  128x128 tile, BK=32, 4 waves.
// Double-buffered LDS + counted vmcnt(4) + raw barriers (T3/T4 minimum) +
// XCD-chunked block swizzle (T1; requires nwg % 8 == 0 -- all our grids).
// EPI: 0 = proj (bias+relu, fp16 store), 1 = scores (mask, fp32 store),
//      2 = pv (plain fp32 store).
// ---------------------------------------------------------------------------
template<int EPI>
__global__ __launch_bounds__(256) void gemm16(
    const unsigned short* __restrict__ Ag, const unsigned short* __restrict__ Bg,
    const float* __restrict__ bias, const int* __restrict__ ymask,
    void* __restrict__ Cg, int K, int NX, int NY,
    size_t a_bs, size_t b_bs, size_t c_bs, int ldc)
{
    __shared__ __attribute__((aligned(16))) unsigned short At[2][128 * 32];
    __shared__ __attribute__((aligned(16))) unsigned short Bt[2][128 * 32];

    // T1: XCD-chunked swizzle of the flat workgroup id (bijective, nwg%8==0)
    const int nwg = NX * NY * (int)gridDim.z;
    const int lid = (int)blockIdx.x + NX * ((int)blockIdx.y + NY * (int)blockIdx.z);
    const int c8  = nwg >> 3;
    const int n   = (lid & 7) * c8 + (lid >> 3);
    const int bx  = n % NX;
    const int rem = n / NX;
    const int by  = rem % NY;
    const int bz  = rem / NY;

    const unsigned short* A = Ag + a_bs * (size_t)bz;
    const unsigned short* B = Bg + b_bs * (size_t)bz;

    const int t    = threadIdx.x;
    const int lane = t & 63;
    const int wave = t >> 6;
    const int wr = wave >> 1, wc = wave & 1;
    const int m0 = by * 128;
    const int n0 = bx * 128;

    const int sr = t >> 2;   // staging row (0..63)
    const int sq = t & 3;    // 16B chunk within 64B k-slice
    const int fr = lane & 15;
    const int kg = lane >> 4;

    const size_t a_row0 = (size_t)(m0 + sr)      * K + sq * 8;
    const size_t a_row1 = (size_t)(m0 + sr + 64) * K + sq * 8;
    const size_t b_row0 = (size_t)(n0 + sr)      * K + sq * 8;
    const size_t b_row1 = (size_t)(n0 + sr + 64) * K + sq * 8;

    f32x4 acc[4][4] = {};

    const int nt = K >> 5;
    int cur = 0;

    // prologue: stage tile 0 into buf 0 (4 loads outstanding)
    gload16(&A[a_row0], &At[0][t * 8]);
    gload16(&A[a_row1], &At[0][2048 + t * 8]);
    gload16(&B[b_row0], &Bt[0][t * 8]);
    gload16(&B[b_row1], &Bt[0][2048 + t * 8]);

    for (int tt = 0; tt < nt; ++tt) {
        if (tt + 1 < nt) {
            // stage tile tt+1 into the other buffer (reads of it finished at
            // the END barrier of iteration tt-1; all waves past it).
            const int k0 = (tt + 1) << 5;
            gload16(&A[a_row0 + k0], &At[cur ^ 1][t * 8]);
            gload16(&A[a_row1 + k0], &At[cur ^ 1][2048 + t * 8]);
            gload16(&B[b_row0 + k0], &Bt[cur ^ 1][t * 8]);
            gload16(&B[b_row1 + k0], &Bt[cur ^ 1][2048 + t * 8]);
            // wait only for the 4 OLDEST loads (tile tt); tile tt+1 stays in flight
            asm volatile("s_waitcnt vmcnt(4)" ::: "memory");
        } else {
            asm volatile("s_waitcnt vmcnt(0)" ::: "memory");
        }
        pipe_barrier();   // tile tt fully visible to all waves

        f16x8 af[4], bf[4];
#pragma unroll
        for (int i = 0; i < 4; ++i) {
            af[i] = __builtin_bit_cast(f16x8, *(const u16x8*)&At[cur][(wr * 64 + i * 16 + fr) * 32 + kg * 8]);
            bf[i] = __builtin_bit_cast(f16x8, *(const u16x8*)&Bt[cur][(wc * 64 + i * 16 + fr) * 32 + kg * 8]);
        }
#pragma unroll
        for (int i = 0; i < 4; ++i)
#pragma unroll
            for (int j = 0; j < 4; ++j)
                acc[i][j] = __builtin_amdgcn_mfma_f32_16x16x32_f16(af[i], bf[j], acc[i][j], 0, 0, 0);

        pipe_barrier();   // all waves done reading buf[cur]; safe to overwrite next iter
        cur ^= 1;
    }

    // epilogue: C/D layout col = lane&15, row = (lane>>4)*4 + reg
    if (EPI == 0) {
        unsigned short* Cp = (unsigned short*)Cg + c_bs * (size_t)bz;
#pragma unroll
        for (int i = 0; i < 4; ++i) {
            int row = m0 + wr * 64 + i * 16 + kg * 4;
#pragma unroll
            for (int j = 0; j < 4; ++j) {
                int col = n0 + wc * 64 + j * 16 + fr;
                float bv = bias[col];
#pragma unroll
                for (int r2 = 0; r2 < 4; ++r2) {
                    float v = acc[i][j][r2] + bv;
                    v = v > 0.f ? v : 0.f;
                    Cp[(size_t)(row + r2) * ldc + col] = f2h(v);
                }
            }
        }
    } else if (EPI == 1) {
        float* Cp = (float*)Cg + c_bs * (size_t)bz;
        const int* mk = ymask + (size_t)(NX * 128) * bz;
#pragma unroll
        for (int i = 0; i < 4; ++i) {
            int row = m0 + wr * 64 + i * 16 + kg * 4;
#pragma unroll
            for (int j = 0; j < 4; ++j) {
                int col = n0 + wc * 64 + j * 16 + fr;
                bool masked = mk[col] != 0;
#pragma unroll
                for (int r2 = 0; r2 < 4; ++r2)
                    Cp[(size_t)(row + r2) * ldc + col] = masked ? -1e30f : acc[i][j][r2];
            }
        }
    } else {
        float* Cp = (float*)Cg + c_bs * (size_t)bz;
#pragma unroll
        for (int i = 0; i < 4; ++i) {
            int row = m0 + wr * 64 + i * 16 + kg * 4;
#pragma unroll
            for (int j = 0; j < 4; ++j) {
                int col = n0 + wc * 64 + j * 16 + fr;
#pragma unroll
                for (int r2 = 0; r2 < 4; ++r2)
                    Cp[(size_t)(row + r2) * ldc + col] = acc[i][j][r2];
            }
        }
    }
}

// ---------------------------------------------------------------------------
// Row softmax.  alpha[row, :] = softmax(S[row, :]) as fp16.
// ---------------------------------------------------------------------------
__global__ __launch_bounds__(256) void softmax_kernel(
    const float* __restrict__ S, unsigned short* __restrict__ alpha)
{
    const size_t row = blockIdx.x;
    const float* s = S + row * 2048;
    unsigned short* a = alpha + row * 2048;
    const int t = threadIdx.x;
    const int lane = t & 63;
    const int wave = t >> 6;

    __shared__ float redm[4];
    __shared__ float reds[4];

    f32x4v v0 = *(const f32x4v*)&s[t * 8];
    f32x4v v1 = *(const f32x4v*)&s[t * 8 + 4];

    float m = -3.4e38f;
#pragma unroll
    for (int e = 0; e < 4; ++e) { m = fmaxf(m, v0[e]); m = fmaxf(m, v1[e]); }
#pragma unroll
    for (int o = 1; o < 64; o <<= 1) m = fmaxf(m, __shfl_xor(m, o));
    if (lane == 0) redm[wave] = m;
    __syncthreads();
    m = fmaxf(fmaxf(redm[0], redm[1]), fmaxf(redm[2], redm[3]));

    float e0[4], e1[4];
    float sum = 0.f;
#pragma unroll
    for (int e = 0; e < 4; ++e) {
        e0[e] = __expf(v0[e] - m); sum += e0[e];
        e1[e] = __expf(v1[e] - m); sum += e1[e];
    }
#pragma unroll
    for (int o = 1; o < 64; o <<= 1) sum += __shfl_xor(sum, o);
    if (lane == 0) reds[wave] = sum;
    __syncthreads();
    sum = reds[0] + reds[1] + reds[2] + reds[3];
    float inv = 1.f / sum;

    u16x4 o0, o1;
#pragma unroll
    for (int e = 0; e < 4; ++e) { o0[e] = f2h(e0[e] * inv); o1[e] = f2h(e1[e] * inv); }
    *(u16x4*)&a[t * 8]     = o0;
    *(u16x4*)&a[t * 8 + 4] = o1;
}

// ---------------------------------------------------------------------------
// y transpose+convert.  yT[b][h][j] fp16 from y[b][j][h] fp32.
// 64x64 tiles via LDS (fp32 [64][65], pad kills bank conflicts both sides).
// ---------------------------------------------------------------------------
__global__ __launch_bounds__(256) void transpose_y_kernel(
    const float* __restrict__ Y, unsigned short* __restrict__ YT)
{
    __shared__ float T[64][65];
    const int b  = blockIdx.z;
    const float* Yb = Y + (size_t)b * 2048 * 1024;
    unsigned short* Tb = YT + (size_t)b * 1024 * 2048;
    const int j0 = blockIdx.y * 64;
    const int h0 = blockIdx.x * 64;
    const int t = threadIdx.x;

    const int jr = t >> 4;    // 0..15
    const int hc = t & 15;    // float4 chunk
#pragma unroll
    for (int p = 0; p < 4; ++p) {
        int j = jr + p * 16;
        f32x4v v = *(const f32x4v*)&Yb[(size_t)(j0 + j) * 1024 + h0 + hc * 4];
#pragma unroll
        for (int e = 0; e < 4; ++e) T[j][hc * 4 + e] = v[e];
    }
    __syncthreads();

    const int hr = t >> 3;    // 0..31
    const int jc = t & 7;     // u16x8 chunk
#pragma unroll
    for (int p = 0; p < 2; ++p) {
        int h = hr + p * 32;
        u16x8 o;
#pragma unroll
        for (int e = 0; e < 8; ++e) o[e] = f2h(T[jc * 8 + e][h]);
        *(u16x8*)&Tb[(size_t)(h0 + h) * 2048 + j0 + jc * 8] = o;
    }
}

// ---------------------------------------------------------------------------
extern "C" void kernel_launch(void* const* d_in, const int* in_sizes, int n_in,
                              void* d_out, int out_size, void* d_ws, size_t ws_size,
                              hipStream_t stream)
{
    const float* x     = (const float*)d_in[0];   // [16, 2048, 1024]
    const float* y     = (const float*)d_in[1];   // [16, 2048, 1024]
    const int*   ymask = (const int*)d_in[2];     // [16, 2048]
    const float* W     = (const float*)d_in[3];   // [1024, 1024]
    const float* bias  = (const float*)d_in[4];   // [1024]
    float* out = (float*)d_out;                   // [16, 2048, 1024] fp32

    // workspace (384 MiB), time-multiplexed:
    //  convert:   Wh@0 (2M), xh@4M (64M), yh@68M (64M)     [inside future-S]
    //  proj-x:    xh,Wh -> xp@256M (64M)
    //  proj-y:    yh,Wh -> yp@320M (64M)
    //  scores:    xp,yp -> S@0 (256M)      [kills Wh/xh/yh]
    //  softmax:   S -> alpha@256M (128M)   [kills xp/yp]
    //  transpose: y -> yT@0 (64M)          [kills S]
    //  pv:        alpha,yT -> out
    const size_t NEED = 402653184; // 384 MiB
    if (ws_size < NEED) return;

    char* ws = (char*)d_ws;
    unsigned short* Wh    = (unsigned short*)(ws + 0);
    unsigned short* xh    = (unsigned short*)(ws + 4194304);
    unsigned short* yh    = (unsigned short*)(ws + 71303168);
    unsigned short* xp    = (unsigned short*)(ws + 268435456);
    unsigned short* yp    = (unsigned short*)(ws + 335544320);
    float*          S     = (float*)(ws + 0);
    unsigned short* alpha = (unsigned short*)(ws + 268435456);
    unsigned short* yT    = (unsigned short*)(ws + 0);

    dim3 blk(256);
    const int n8xy = (16 * 2048 * 1024) / 8;
    cvt_kernel<<<dim3(2048), blk, 0, stream>>>(x, xh, n8xy);
    cvt_kernel<<<dim3(2048), blk, 0, stream>>>(y, yh, n8xy);
    cvt_kernel<<<dim3(512),  blk, 0, stream>>>(W, Wh, (1024 * 1024) / 8);

    gemm16<0><<<dim3(8, 256, 1), blk, 0, stream>>>(
        xh, Wh, bias, nullptr, xp, 1024, 8, 256, 0, 0, 0, 1024);
    gemm16<0><<<dim3(8, 256, 1), blk, 0, stream>>>(
        yh, Wh, bias, nullptr, yp, 1024, 8, 256, 0, 0, 0, 1024);

    gemm16<1><<<dim3(16, 16, 16), blk, 0, stream>>>(
        xp, yp, nullptr, ymask, S, 1024, 16, 16,
        (size_t)2048 * 1024, (size_t)2048 * 1024, (size_t)2048 * 2048, 2048);

    softmax_kernel<<<dim3(32768), blk, 0, stream>>>(S, alpha);
    transpose_y_kernel<<<dim3(16, 32, 16), blk, 0, stream>>>(y, yT);

    gemm16<2><<<dim3(8, 16, 16), blk, 0, stream>>>(
        alpha, yT, nullptr, nullptr, out, 2048, 8, 16,
        (size_t)2048 * 2048, (size_t)1024 * 2048, (size_t)2048 * 1024, 1024);
}

// Round 8
// 907.370 us; speedup vs baseline: 2.0545x; 1.0902x over previous
//
#include <hip/hip_runtime.h>
#include <hip/hip_bf16.h>
#include <hip/hip_fp16.h>

#define DEVINL __device__ __forceinline__

typedef _Float16 f16x8 __attribute__((ext_vector_type(8)));
typedef float f32x4 __attribute__((ext_vector_type(4)));
typedef float f32x4v __attribute__((ext_vector_type(4)));
typedef unsigned short u16x4 __attribute__((ext_vector_type(4)));
typedef unsigned short u16x8 __attribute__((ext_vector_type(8)));

DEVINL unsigned short f2h(float x) {
    _Float16 h = (_Float16)x;
    return __builtin_bit_cast(unsigned short, h);
}

// async global->LDS, 16B per lane. LDS dest must be linear (base + lane*16).
DEVINL void gload16(const void* g, void* l) {
    __builtin_amdgcn_global_load_lds(
        (const __attribute__((address_space(1))) void*)g,
        (__attribute__((address_space(3))) void*)l, 16, 0, 0);
}

// raw barrier fenced against compiler reordering (no vmcnt(0) drain)
#define PB() do { asm volatile("" ::: "memory"); \
                  __builtin_amdgcn_s_barrier(); \
                  asm volatile("" ::: "memory"); } while (0)
#define LGKM() asm volatile("s_waitcnt lgkmcnt(0)" ::: "memory")
#define VM(n_) asm volatile("s_waitcnt vmcnt(" #n_ ")" ::: "memory")

// ---------------------------------------------------------------------------
// fp32 -> fp16 convert
// ---------------------------------------------------------------------------
__global__ __launch_bounds__(256) void cvt_kernel(
    const float* __restrict__ in, unsigned short* __restrict__ out, int n8)
{
    int i = blockIdx.x * 256 + threadIdx.x;
    int stride = gridDim.x * 256;
    for (; i < n8; i += stride) {
        f32x4v a = *(const f32x4v*)&in[(size_t)i * 8];
        f32x4v b = *(const f32x4v*)&in[(size_t)i * 8 + 4];
        u16x8 o;
#pragma unroll
        for (int e = 0; e < 4; ++e) { o[e] = f2h(a[e]); o[4 + e] = f2h(b[e]); }
        *(u16x8*)&out[(size_t)i * 8] = o;
    }
}

// ---------------------------------------------------------------------------
// 256x256 8-phase pipelined GEMM:  C[m,n] = sum_k A[m,k] * B[n,k]
// A,B fp16 k-contiguous. BK=64 (2 K-tiles/iter), 8 waves (2M x 4N).
// LDS regions: {dbuf}x{khalf}x{A,B} = 8 x 16KiB (256 rows x 32 k fp16).
// Per phase: {ds_read frags || stage 1 half-tile} -> barrier -> lgkmcnt(0)
//            -> setprio(1) + 16 MFMA + setprio(0) -> barrier.
// vmcnt(6) at phases 4,8 only (3 half-tiles stay in flight). T2 chunk-XOR
// swizzle applied on BOTH the gload global source and the ds_read address.
// Stage schedule (iter i computes K-tiles 2i[dbuf0], 2i+1[dbuf1]):
//  ph1:A11<-2i+1  ph2:B00<-2i+2  ph3:A00<-2i+2  ph4:B01<-2i+2 +vm6
//  ph5:A01<-2i+2  ph6:B10<-2i+3  ph7:A10<-2i+3  ph8:B11<-2i+3 +vm6
// Each region: staged >= last-read+1 (barrier between); first-read covered by
// a vmcnt(6)+barrier at least 3 staged half-tiles later.  Tail prefetches are
// clamped to k-tile 0 (written, never read).
// ---------------------------------------------------------------------------
template<int EPI>
__global__ __launch_bounds__(512, 2) void gemm256(
    const unsigned short* __restrict__ Ag, const unsigned short* __restrict__ Bg,
    const float* __restrict__ bias, const int* __restrict__ ymask,
    void* __restrict__ Cg, int K, int NX, int NY,
    size_t a_bs, size_t b_bs, size_t c_bs, int ldc)
{
    __shared__ __attribute__((aligned(16))) unsigned short LA[2][2][8192];
    __shared__ __attribute__((aligned(16))) unsigned short LB[2][2][8192];

    // T1: XCD-chunked bijective swizzle (all grids have nwg % 8 == 0)
    const int nwg = NX * NY * (int)gridDim.z;
    const int lid = (int)blockIdx.x + NX * ((int)blockIdx.y + NY * (int)blockIdx.z);
    const int c8  = nwg >> 3;
    const int sw  = (lid & 7) * c8 + (lid >> 3);
    const int bx  = sw % NX;
    const int rem = sw / NX;
    const int by  = rem % NY;
    const int bz  = rem / NY;

    const unsigned short* A = Ag + a_bs * (size_t)bz;
    const unsigned short* B = Bg + b_bs * (size_t)bz;

    const int t    = threadIdx.x;
    const int lane = t & 63;
    const int wave = t >> 6;
    const int wrm  = wave >> 2;   // M half (0..1) -> 128 rows
    const int wcn  = wave & 3;    // N quarter (0..3) -> 64 cols
    const int fr   = lane & 15;
    const int kg   = lane >> 4;
    const int m0   = by * 256;
    const int n0   = bx * 256;

    // staging: thread t covers (row = q*128 + t>>2, chunk = t&3) of a region;
    // source chunk pre-swizzled so linear LDS holds swizzled layout
    const int s_row   = t >> 2;
    const int s_chunk = (t & 3) ^ ((t >> 3) & 3);
    // read-side swizzled 16B-granule (elements)
    const int rchunk  = (kg ^ ((fr >> 1) & 3)) * 8;

    const int NT2 = K >> 6;   // 64-wide K-tiles
    const int NI  = K >> 7;   // iterations (2 K-tiles each)

    f32x4 acc[8][4] = {};
    f16x8 afr[4], bfr[4];

#define STA(d, h, kt_) do { int kt__ = (kt_) < NT2 ? (kt_) : 0; \
    size_t go__ = (size_t)(m0 + s_row) * K + kt__ * 64 + (h) * 32 + s_chunk * 8; \
    gload16(&A[go__], &LA[d][h][t * 8]); \
    gload16(&A[go__ + (size_t)128 * K], &LA[d][h][4096 + t * 8]); } while (0)

#define STB(d, h, kt_) do { int kt__ = (kt_) < NT2 ? (kt_) : 0; \
    size_t go__ = (size_t)(n0 + s_row) * K + kt__ * 64 + (h) * 32 + s_chunk * 8; \
    gload16(&B[go__], &LB[d][h][t * 8]); \
    gload16(&B[go__ + (size_t)128 * K], &LB[d][h][4096 + t * 8]); } while (0)

#define DSA(d, h, g) do { _Pragma("unroll") \
    for (int f_ = 0; f_ < 4; ++f_) \
        afr[f_] = __builtin_bit_cast(f16x8, *(const u16x8*)&LA[d][h][ \
            (wrm * 128 + (g) * 64 + f_ * 16 + fr) * 32 + rchunk]); } while (0)

#define DSB(d, h) do { _Pragma("unroll") \
    for (int j_ = 0; j_ < 4; ++j_) \
        bfr[j_] = __builtin_bit_cast(f16x8, *(const u16x8*)&LB[d][h][ \
            (wcn * 64 + j_ * 16 + fr) * 32 + rchunk]); } while (0)

#define MMA(g) do { __builtin_amdgcn_s_setprio(1); \
    _Pragma("unroll") for (int f_ = 0; f_ < 4; ++f_) \
    _Pragma("unroll") for (int j_ = 0; j_ < 4; ++j_) \
        acc[(g) * 4 + f_][j_] = __builtin_amdgcn_mfma_f32_16x16x32_f16( \
            afr[f_], bfr[j_], acc[(g) * 4 + f_][j_], 0, 0, 0); \
    __builtin_amdgcn_s_setprio(0); } while (0)

    // prologue: 4 half-tiles, vmcnt(4), 3 more, vmcnt(6), barrier
    STA(0, 0, 0); STB(0, 0, 0); STA(0, 1, 0); STB(0, 1, 0);
    VM(4);
    STA(1, 0, 1); STB(1, 0, 1); STB(1, 1, 1);
    VM(6);
    PB();

    for (int i = 0; i < NI; ++i) {
        const int kb = 2 * i + 1, n2 = 2 * i + 2, n3 = 2 * i + 3;
        // ph1: dbuf0 khalf0, Mgroup0
        DSA(0, 0, 0); DSB(0, 0); STA(1, 1, kb);
        PB(); LGKM(); MMA(0); PB();
        // ph2: dbuf0 khalf0, Mgroup1 (B reused in regs)
        DSA(0, 0, 1); STB(0, 0, n2);
        PB(); LGKM(); MMA(1); PB();
        // ph3: dbuf0 khalf1, Mgroup0
        DSA(0, 1, 0); DSB(0, 1); STA(0, 0, n2);
        PB(); LGKM(); MMA(0); PB();
        // ph4: dbuf0 khalf1, Mgroup1
        DSA(0, 1, 1); STB(0, 1, n2); VM(6);
        PB(); LGKM(); MMA(1); PB();
        // ph5: dbuf1 khalf0, Mgroup0
        DSA(1, 0, 0); DSB(1, 0); STA(0, 1, n2);
        PB(); LGKM(); MMA(0); PB();
        // ph6: dbuf1 khalf0, Mgroup1
        DSA(1, 0, 1); STB(1, 0, n3);
        PB(); LGKM(); MMA(1); PB();
        // ph7: dbuf1 khalf1, Mgroup0
        DSA(1, 1, 0); DSB(1, 1); STA(1, 0, n3);
        PB(); LGKM(); MMA(0); PB();
        // ph8: dbuf1 khalf1, Mgroup1
        DSA(1, 1, 1); STB(1, 1, n3); VM(6);
        PB(); LGKM(); MMA(1); PB();
    }

    VM(0);   // drain clamped tail prefetches before block exit

    // epilogue: C/D layout col = lane&15, row = (lane>>4)*4 + reg
#pragma unroll
    for (int g = 0; g < 2; ++g)
#pragma unroll
    for (int f = 0; f < 4; ++f) {
        const int rbase = m0 + wrm * 128 + g * 64 + f * 16 + kg * 4;
        if (EPI == 0) {
            unsigned short* Cp = (unsigned short*)Cg + c_bs * (size_t)bz;
#pragma unroll
            for (int j = 0; j < 4; ++j) {
                int col = n0 + wcn * 64 + j * 16 + fr;
                float bv = bias[col];
#pragma unroll
                for (int r2 = 0; r2 < 4; ++r2) {
                    float v = acc[g * 4 + f][j][r2] + bv;
                    v = v > 0.f ? v : 0.f;
                    Cp[(size_t)(rbase + r2) * ldc + col] = f2h(v);
                }
            }
        } else if (EPI == 1) {
            float* Cp = (float*)Cg + c_bs * (size_t)bz;
            const int* mk = ymask + (size_t)(NX * 256) * bz;
#pragma unroll
            for (int j = 0; j < 4; ++j) {
                int col = n0 + wcn * 64 + j * 16 + fr;
                bool masked = mk[col] != 0;
#pragma unroll
                for (int r2 = 0; r2 < 4; ++r2)
                    Cp[(size_t)(rbase + r2) * ldc + col] = masked ? -1e30f : acc[g * 4 + f][j][r2];
            }
        } else {
            float* Cp = (float*)Cg + c_bs * (size_t)bz;
#pragma unroll
            for (int j = 0; j < 4; ++j) {
                int col = n0 + wcn * 64 + j * 16 + fr;
#pragma unroll
                for (int r2 = 0; r2 < 4; ++r2)
                    Cp[(size_t)(rbase + r2) * ldc + col] = acc[g * 4 + f][j][r2];
            }
        }
    }
#undef STA
#undef STB
#undef DSA
#undef DSB
#undef MMA
}

// ---------------------------------------------------------------------------
// Row softmax.  alpha[row, :] = softmax(S[row, :]) as fp16.
// ---------------------------------------------------------------------------
__global__ __launch_bounds__(256) void softmax_kernel(
    const float* __restrict__ S, unsigned short* __restrict__ alpha)
{
    const size_t row = blockIdx.x;
    const float* s = S + row * 2048;
    unsigned short* a = alpha + row * 2048;
    const int t = threadIdx.x;
    const int lane = t & 63;
    const int wave = t >> 6;

    __shared__ float redm[4];
    __shared__ float reds[4];

    f32x4v v0 = *(const f32x4v*)&s[t * 8];
    f32x4v v1 = *(const f32x4v*)&s[t * 8 + 4];

    float m = -3.4e38f;
#pragma unroll
    for (int e = 0; e < 4; ++e) { m = fmaxf(m, v0[e]); m = fmaxf(m, v1[e]); }
#pragma unroll
    for (int o = 1; o < 64; o <<= 1) m = fmaxf(m, __shfl_xor(m, o));
    if (lane == 0) redm[wave] = m;
    __syncthreads();
    m = fmaxf(fmaxf(redm[0], redm[1]), fmaxf(redm[2], redm[3]));

    float e0[4], e1[4];
    float sum = 0.f;
#pragma unroll
    for (int e = 0; e < 4; ++e) {
        e0[e] = __expf(v0[e] - m); sum += e0[e];
        e1[e] = __expf(v1[e] - m); sum += e1[e];
    }
#pragma unroll
    for (int o = 1; o < 64; o <<= 1) sum += __shfl_xor(sum, o);
    if (lane == 0) reds[wave] = sum;
    __syncthreads();
    sum = reds[0] + reds[1] + reds[2] + reds[3];
    float inv = 1.f / sum;

    u16x4 o0, o1;
#pragma unroll
    for (int e = 0; e < 4; ++e) { o0[e] = f2h(e0[e] * inv); o1[e] = f2h(e1[e] * inv); }
    *(u16x4*)&a[t * 8]     = o0;
    *(u16x4*)&a[t * 8 + 4] = o1;
}

// ---------------------------------------------------------------------------
// y transpose+convert.  yT[b][h][j] fp16 from y[b][j][h] fp32.
// ---------------------------------------------------------------------------
__global__ __launch_bounds__(256) void transpose_y_kernel(
    const float* __restrict__ Y, unsigned short* __restrict__ YT)
{
    __shared__ float T[64][65];
    const int b  = blockIdx.z;
    const float* Yb = Y + (size_t)b * 2048 * 1024;
    unsigned short* Tb = YT + (size_t)b * 1024 * 2048;
    const int j0 = blockIdx.y * 64;
    const int h0 = blockIdx.x * 64;
    const int t = threadIdx.x;

    const int jr = t >> 4;
    const int hc = t & 15;
#pragma unroll
    for (int p = 0; p < 4; ++p) {
        int j = jr + p * 16;
        f32x4v v = *(const f32x4v*)&Yb[(size_t)(j0 + j) * 1024 + h0 + hc * 4];
#pragma unroll
        for (int e = 0; e < 4; ++e) T[j][hc * 4 + e] = v[e];
    }
    __syncthreads();

    const int hr = t >> 3;
    const int jc = t & 7;
#pragma unroll
    for (int p = 0; p < 2; ++p) {
        int h = hr + p * 32;
        u16x8 o;
#pragma unroll
        for (int e = 0; e < 8; ++e) o[e] = f2h(T[jc * 8 + e][h]);
        *(u16x8*)&Tb[(size_t)(h0 + h) * 2048 + j0 + jc * 8] = o;
    }
}

// ---------------------------------------------------------------------------
extern "C" void kernel_launch(void* const* d_in, const int* in_sizes, int n_in,
                              void* d_out, int out_size, void* d_ws, size_t ws_size,
                              hipStream_t stream)
{
    const float* x     = (const float*)d_in[0];   // [16, 2048, 1024]
    const float* y     = (const float*)d_in[1];   // [16, 2048, 1024]
    const int*   ymask = (const int*)d_in[2];     // [16, 2048]
    const float* W     = (const float*)d_in[3];   // [1024, 1024]
    const float* bias  = (const float*)d_in[4];   // [1024]
    float* out = (float*)d_out;                   // [16, 2048, 1024] fp32

    // workspace (384 MiB), time-multiplexed:
    //  convert:   Wh@0 (2M), xh@4M (64M), yh@68M (64M)     [inside future-S]
    //  proj-x:    xh,Wh -> xp@256M; proj-y: yh,Wh -> yp@320M
    //  scores:    xp,yp -> S@0 (256M)      [kills Wh/xh/yh]
    //  softmax:   S -> alpha@256M (128M)   [kills xp/yp]
    //  transpose: y -> yT@0 (64M)          [kills S]
    //  pv:        alpha,yT -> out
    const size_t NEED = 402653184; // 384 MiB
    if (ws_size < NEED) return;

    char* ws = (char*)d_ws;
    unsigned short* Wh    = (unsigned short*)(ws + 0);
    unsigned short* xh    = (unsigned short*)(ws + 4194304);
    unsigned short* yh    = (unsigned short*)(ws + 71303168);
    unsigned short* xp    = (unsigned short*)(ws + 268435456);
    unsigned short* yp    = (unsigned short*)(ws + 335544320);
    float*          S     = (float*)(ws + 0);
    unsigned short* alpha = (unsigned short*)(ws + 268435456);
    unsigned short* yT    = (unsigned short*)(ws + 0);

    dim3 blk(256);
    dim3 blk512(512);
    const int n8xy = (16 * 2048 * 1024) / 8;
    cvt_kernel<<<dim3(2048), blk, 0, stream>>>(x, xh, n8xy);
    cvt_kernel<<<dim3(2048), blk, 0, stream>>>(y, yh, n8xy);
    cvt_kernel<<<dim3(512),  blk, 0, stream>>>(W, Wh, (1024 * 1024) / 8);

    // proj: M=32768 (flattened b*i), N=1024, K=1024
    gemm256<0><<<dim3(4, 128, 1), blk512, 0, stream>>>(
        xh, Wh, bias, nullptr, xp, 1024, 4, 128, 0, 0, 0, 1024);
    gemm256<0><<<dim3(4, 128, 1), blk512, 0, stream>>>(
        yh, Wh, bias, nullptr, yp, 1024, 4, 128, 0, 0, 0, 1024);

    // scores: per batch M=N=2048, K=1024
    gemm256<1><<<dim3(8, 8, 16), blk512, 0, stream>>>(
        xp, yp, nullptr, ymask, S, 1024, 8, 8,
        (size_t)2048 * 1024, (size_t)2048 * 1024, (size_t)2048 * 2048, 2048);

    softmax_kernel<<<dim3(32768), blk, 0, stream>>>(S, alpha);
    transpose_y_kernel<<<dim3(16, 32, 16), blk, 0, stream>>>(y, yT);

    // pv: per batch M=2048, N=1024, K=2048
    gemm256<2><<<dim3(4, 8, 16), blk512, 0, stream>>>(
        alpha, yT, nullptr, nullptr, out, 2048, 4, 8,
        (size_t)2048 * 2048, (size_t)1024 * 2048, (size_t)2048 * 1024, 1024);
}